// Round 3
// baseline (82.867 us; speedup 1.0000x reference)
//
#include <hip/hip_runtime.h>

#define T_LEN 16384
#define B_COLS 2048
#define CHUNK 256      // output samples per thread
#define WARM 24        // warm-up samples (max pole radius 0.758 -> 0.758^24 ~ 1.3e-3)
#define UNR 16         // main-loop unroll: 32 loads in flight per thread for MLP

// One thread per (column, time-chunk). Exact head handling for chunk 0;
// zero-state warm-up for chunks >= 1.
// Grid: 64 chunks x 8 col-blocks = 512 blocks x 256 thr = 2048 waves; MLP via unroll-16.
__global__ __launch_bounds__(256) void lowpass_kernel(
    const float* __restrict__ sig,   // (2, T, B) float32
    const float* __restrict__ bc,    // 5 taps
    const float* __restrict__ ac,    // [a4, a3, a2, a1, -1] (pre-reversed by setup)
    float* __restrict__ out)         // (T, B) float32
{
    const int col   = ((blockIdx.x & 7) << 8) + threadIdx.x;  // 8 column-blocks of 256
    const int chunk = blockIdx.x >> 3;                        // 64 time-chunks

    const float* __restrict__ s0 = sig;
    const float* __restrict__ s1 = sig + (size_t)T_LEN * B_COLS;

    // coefficients (uniform -> scalar loads)
    const float b0 = bc[0], b1 = bc[1], b2 = bc[2], b3 = bc[3], b4 = bc[4];
    const float na0 = -ac[0], na1 = -ac[1], na2 = -ac[2], na3 = -ac[3];

    // FIR window x[t-4..t-1] and IIR carry y[t-4..t-1]
    float x1 = 0.f, x2 = 0.f, x3 = 0.f, x4 = 0.f;
    float c0 = 0.f, c1 = 0.f, c2 = 0.f, c3 = 0.f;

    const int t_start = chunk * CHUNK;
    const int t_end   = t_start + CHUNK;
    int t;

    if (chunk == 0) {
        // Exact head: y[t] = xf[t] for t = 0..4; carry ends as [xf1,xf2,xf3,xf4]
        for (t = 0; t < 5; ++t) {
            size_t idx = (size_t)t * B_COLS + col;
            float v0 = s0[idx], v1 = s1[idx];
            float x0 = v0 * v0 + v1 * v1;
            float xf = b0 * x4 + b1 * x3 + b2 * x2 + b3 * x1 + b4 * x0;
            __builtin_nontemporal_store(xf, &out[idx]);
            x4 = x3; x3 = x2; x2 = x1; x1 = x0;
            c0 = c1; c1 = c2; c2 = c3; c3 = xf;
        }
        t = 5;
    } else {
        const int tw = t_start - WARM;   // >= 232, always valid
        // Preload FIR window x[tw-4..tw-1]
        {
            size_t base = (size_t)(tw - 4) * B_COLS + col;
            float v0, v1;
            v0 = s0[base];              v1 = s1[base];              x4 = v0*v0 + v1*v1;
            v0 = s0[base +   B_COLS];   v1 = s1[base +   B_COLS];   x3 = v0*v0 + v1*v1;
            v0 = s0[base + 2*B_COLS];   v1 = s1[base + 2*B_COLS];   x2 = v0*v0 + v1*v1;
            v0 = s0[base + 3*B_COLS];   v1 = s1[base + 3*B_COLS];   x1 = v0*v0 + v1*v1;
        }
        // Warm-up: run recursion from zero state, discard outputs (24 iters)
        #pragma unroll 8
        for (t = tw; t < t_start; ++t) {
            size_t idx = (size_t)t * B_COLS + col;
            float v0 = s0[idx], v1 = s1[idx];
            float x0 = v0 * v0 + v1 * v1;
            float xf = b0 * x4 + b1 * x3 + b2 * x2 + b3 * x1 + b4 * x0;
            float y  = xf + na0 * c0 + na1 * c1 + na2 * c2 + na3 * c3;
            x4 = x3; x3 = x2; x2 = x1; x1 = x0;
            c0 = c1; c1 = c2; c2 = c3; c3 = y;
        }
        t = t_start;
    }

    // Scalar iterations until t is UNR-aligned (only chunk 0: t=5..16)
    for (; t < t_end && (t & (UNR - 1)); ++t) {
        size_t idx = (size_t)t * B_COLS + col;
        float v0 = s0[idx], v1 = s1[idx];
        float x0 = v0 * v0 + v1 * v1;
        float xf = b0 * x4 + b1 * x3 + b2 * x2 + b3 * x1 + b4 * x0;
        float y  = xf + na0 * c0 + na1 * c1 + na2 * c2 + na3 * c3;
        __builtin_nontemporal_store(y, &out[idx]);
        x4 = x3; x3 = x2; x2 = x1; x1 = x0;
        c0 = c1; c1 = c2; c2 = c3; c3 = y;
    }

    // Main loop: batch 2*UNR loads, then run the serial recursion over UNR rows.
    for (; t < t_end; t += UNR) {
        float u0[UNR], u1[UNR];
        #pragma unroll
        for (int j = 0; j < UNR; ++j) {
            size_t idx = (size_t)(t + j) * B_COLS + col;
            u0[j] = s0[idx];
            u1[j] = s1[idx];
        }
        #pragma unroll
        for (int j = 0; j < UNR; ++j) {
            float x0 = u0[j] * u0[j] + u1[j] * u1[j];
            float xf = b0 * x4 + b1 * x3 + b2 * x2 + b3 * x1 + b4 * x0;
            float y  = xf + na0 * c0 + na1 * c1 + na2 * c2 + na3 * c3;
            __builtin_nontemporal_store(y, &out[(size_t)(t + j) * B_COLS + col]);
            x4 = x3; x3 = x2; x2 = x1; x1 = x0;
            c0 = c1; c1 = c2; c2 = c3; c3 = y;
        }
    }
}

extern "C" void kernel_launch(void* const* d_in, const int* in_sizes, int n_in,
                              void* d_out, int out_size, void* d_ws, size_t ws_size,
                              hipStream_t stream) {
    const float* sig = (const float*)d_in[0];
    const float* b   = (const float*)d_in[1];
    const float* a   = (const float*)d_in[2];
    float* out = (float*)d_out;

    const int col_blocks = B_COLS / 256;         // 8
    const int chunks     = T_LEN / CHUNK;        // 64
    dim3 grid(col_blocks * chunks);              // 512 blocks
    dim3 block(256);
    lowpass_kernel<<<grid, block, 0, stream>>>(sig, b, a, out);
}

// Round 4
// 74.886 us; speedup vs baseline: 1.1066x; 1.1066x over previous
//
#include <hip/hip_runtime.h>

#define T_LEN 16384
#define B_COLS 2048
#define CHUNK 128      // output samples per thread -> 4096 waves (4/SIMD), proven 6.15 TB/s
#define WARM 24        // warm-up samples (max pole radius 0.758 -> 0.758^24 ~ 1.3e-3)

// One thread per (column, time-chunk). Exact head handling for chunk 0;
// zero-state warm-up for chunks >= 1.
// Grid: 128 chunks x 8 col-blocks = 1024 blocks x 256 thr = 4096 waves (4/SIMD).
__global__ __launch_bounds__(256) void lowpass_kernel(
    const float* __restrict__ sig,   // (2, T, B) float32
    const float* __restrict__ bc,    // 5 taps
    const float* __restrict__ ac,    // [a4, a3, a2, a1, -1] (pre-reversed by setup)
    float* __restrict__ out)         // (T, B) float32
{
    const int col   = ((blockIdx.x & 7) << 8) + threadIdx.x;  // 8 column-blocks of 256
    const int chunk = blockIdx.x >> 3;                        // 128 time-chunks

    const float* __restrict__ s0 = sig;
    const float* __restrict__ s1 = sig + (size_t)T_LEN * B_COLS;

    // coefficients (uniform -> scalar loads)
    const float b0 = bc[0], b1 = bc[1], b2 = bc[2], b3 = bc[3], b4 = bc[4];
    const float na0 = -ac[0], na1 = -ac[1], na2 = -ac[2], na3 = -ac[3];

    // FIR window x[t-4..t-1] and IIR carry y[t-4..t-1]
    float x1 = 0.f, x2 = 0.f, x3 = 0.f, x4 = 0.f;
    float c0 = 0.f, c1 = 0.f, c2 = 0.f, c3 = 0.f;

    const int t_start = chunk * CHUNK;
    int t;

    if (chunk == 0) {
        // Exact head: y[t] = xf[t] for t = 0..4; carry ends as [xf1,xf2,xf3,xf4]
        for (t = 0; t < 5; ++t) {
            size_t idx = (size_t)t * B_COLS + col;
            float v0 = s0[idx], v1 = s1[idx];
            float x0 = v0 * v0 + v1 * v1;
            float xf = b0 * x4 + b1 * x3 + b2 * x2 + b3 * x1 + b4 * x0;
            __builtin_nontemporal_store(xf, &out[idx]);
            x4 = x3; x3 = x2; x2 = x1; x1 = x0;
            c0 = c1; c1 = c2; c2 = c3; c3 = xf;
        }
        t = 5;
    } else {
        const int tw = t_start - WARM;   // >= 104, always valid (tw-4 >= 100)
        // Preload FIR window x[tw-4..tw-1]
        {
            size_t base = (size_t)(tw - 4) * B_COLS + col;
            float v0, v1;
            v0 = s0[base];              v1 = s1[base];              x4 = v0*v0 + v1*v1;
            v0 = s0[base +   B_COLS];   v1 = s1[base +   B_COLS];   x3 = v0*v0 + v1*v1;
            v0 = s0[base + 2*B_COLS];   v1 = s1[base + 2*B_COLS];   x2 = v0*v0 + v1*v1;
            v0 = s0[base + 3*B_COLS];   v1 = s1[base + 3*B_COLS];   x1 = v0*v0 + v1*v1;
        }
        // Warm-up: run recursion from zero state, discard outputs (24 iters)
        #pragma unroll 8
        for (t = tw; t < t_start; ++t) {
            size_t idx = (size_t)t * B_COLS + col;
            float v0 = s0[idx], v1 = s1[idx];
            float x0 = v0 * v0 + v1 * v1;
            float xf = b0 * x4 + b1 * x3 + b2 * x2 + b3 * x1 + b4 * x0;
            float y  = xf + na0 * c0 + na1 * c1 + na2 * c2 + na3 * c3;
            x4 = x3; x3 = x2; x2 = x1; x1 = x0;
            c0 = c1; c1 = c2; c2 = c3; c3 = y;
        }
        t = t_start;
    }

    const int t_end = t_start + CHUNK;
    #pragma unroll 8
    for (; t < t_end; ++t) {
        size_t idx = (size_t)t * B_COLS + col;
        float v0 = s0[idx], v1 = s1[idx];
        float x0 = v0 * v0 + v1 * v1;
        float xf = b0 * x4 + b1 * x3 + b2 * x2 + b3 * x1 + b4 * x0;
        float y  = xf + na0 * c0 + na1 * c1 + na2 * c2 + na3 * c3;
        __builtin_nontemporal_store(y, &out[idx]);
        x4 = x3; x3 = x2; x2 = x1; x1 = x0;
        c0 = c1; c1 = c2; c2 = c3; c3 = y;
    }
}

extern "C" void kernel_launch(void* const* d_in, const int* in_sizes, int n_in,
                              void* d_out, int out_size, void* d_ws, size_t ws_size,
                              hipStream_t stream) {
    const float* sig = (const float*)d_in[0];
    const float* b   = (const float*)d_in[1];
    const float* a   = (const float*)d_in[2];
    float* out = (float*)d_out;

    const int col_blocks = B_COLS / 256;         // 8
    const int chunks     = T_LEN / CHUNK;        // 128
    dim3 grid(col_blocks * chunks);              // 1024 blocks
    dim3 block(256);
    lowpass_kernel<<<grid, block, 0, stream>>>(sig, b, a, out);
}